// Round 1
// baseline (190.003 us; speedup 1.0000x reference)
//
#include <hip/hip_runtime.h>
#include <hip/hip_fp16.h>
#include <math.h>

#define B_ 4
#define T_ 256
#define U_ 48
#define H_ 512
#define V_ 1024
#define BLANK_ (V_-1)

#define GM 1220        // B*T + B*(U+1)
#define GM_ENC 1024    // B*T

// ---------------- Kernel 1: C = [enc;dec] @ W^T  (+bias for enc rows)
// M=1220, N=1024, K=512.  64x64 tile, 256 threads, 4x4 per thread.
__global__ __launch_bounds__(256) void gemm_kernel(
    const float* __restrict__ enc, const float* __restrict__ dec,
    const float* __restrict__ W, const float* __restrict__ bias,
    float* __restrict__ E, float* __restrict__ D)
{
    __shared__ float As[16][68];   // [k][row], pad keeps float4 alignment + conflict-free
    __shared__ float Bs[16][68];   // [k][col]
    const int tid = threadIdx.x;
    const int tx = tid & 15, ty = tid >> 4;
    const int bx = blockIdx.x, by = blockIdx.y;
    const int row0 = by * 64, col0 = bx * 64;

    float acc[4][4] = {};
    const int lrow = tid >> 2;        // 0..63
    const int lk   = (tid & 3) * 4;   // 0,4,8,12

    for (int k0 = 0; k0 < H_; k0 += 16) {
        int gr = row0 + lrow;
        float4 av = make_float4(0.f, 0.f, 0.f, 0.f);
        if (gr < GM) {
            const float* src = (gr < GM_ENC) ? (enc + (size_t)gr * H_)
                                             : (dec + (size_t)(gr - GM_ENC) * H_);
            av = *(const float4*)(src + k0 + lk);
        }
        float4 bv = *(const float4*)(W + (size_t)(col0 + lrow) * H_ + k0 + lk);
        __syncthreads();
        As[lk + 0][lrow] = av.x; As[lk + 1][lrow] = av.y;
        As[lk + 2][lrow] = av.z; As[lk + 3][lrow] = av.w;
        Bs[lk + 0][lrow] = bv.x; Bs[lk + 1][lrow] = bv.y;
        Bs[lk + 2][lrow] = bv.z; Bs[lk + 3][lrow] = bv.w;
        __syncthreads();
        #pragma unroll
        for (int k = 0; k < 16; ++k) {
            float4 a = *(const float4*)&As[k][ty * 4];
            float4 b = *(const float4*)&Bs[k][tx * 4];
            float ar[4] = {a.x, a.y, a.z, a.w};
            float br[4] = {b.x, b.y, b.z, b.w};
            #pragma unroll
            for (int i = 0; i < 4; ++i)
                #pragma unroll
                for (int j = 0; j < 4; ++j)
                    acc[i][j] += ar[i] * br[j];
        }
    }
    #pragma unroll
    for (int i = 0; i < 4; ++i) {
        int r = row0 + ty * 4 + i;
        if (r >= GM) continue;
        int c = col0 + tx * 4;
        if (r < GM_ENC) {
            float4 bb = *(const float4*)(bias + c);
            float4 o = make_float4(acc[i][0] + bb.x, acc[i][1] + bb.y,
                                   acc[i][2] + bb.z, acc[i][3] + bb.w);
            *(float4*)(E + (size_t)r * V_ + c) = o;
        } else {
            float4 o = make_float4(acc[i][0], acc[i][1], acc[i][2], acc[i][3]);
            *(float4*)(D + (size_t)(r - GM_ENC) * V_ + c) = o;
        }
    }
}

// ---------------- Kernel 2: per (b,t) cell: LSE over V of E[b,t,:]+D[b,u,:]
// writes lp_blank [b][u][t] and lp_label [b][u][t]  (transposed for DP kernel)
__global__ __launch_bounds__(256) void lse_kernel(
    const float* __restrict__ E, const float* __restrict__ D,
    const int* __restrict__ targets,
    float* __restrict__ lpb, float* __restrict__ lpl)
{
    __shared__ float Es[V_];
    const int bt = blockIdx.x;            // 0..B*T-1
    const int b = bt >> 8, t = bt & 255;
    const int tid = threadIdx.x;

    *(float4*)(Es + tid * 4) = *(const float4*)(E + (size_t)bt * V_ + tid * 4);
    __syncthreads();

    const int wave = tid >> 6, lane = tid & 63;
    for (int u = wave; u <= U_; u += 4) {
        const float* Drow = D + (size_t)(b * (U_ + 1) + u) * V_;
        float vals[16];
        float m = -INFINITY;
        #pragma unroll
        for (int j = 0; j < 16; ++j) {
            int v = j * 64 + lane;               // strided: conflict-free LDS, coalesced global
            vals[j] = Es[v] + Drow[v];
            m = fmaxf(m, vals[j]);
        }
        #pragma unroll
        for (int off = 32; off; off >>= 1)
            m = fmaxf(m, __shfl_xor(m, off));
        float s = 0.f;
        #pragma unroll
        for (int j = 0; j < 16; ++j)
            s += __expf(vals[j] - m);
        #pragma unroll
        for (int off = 32; off; off >>= 1)
            s += __shfl_xor(s, off);
        float lse = m + __logf(s);
        if (lane == 0) {
            lpb[(b * (U_ + 1) + u) * T_ + t] = Es[BLANK_] + Drow[BLANK_] - lse;
            if (u < U_) {
                int tgt = targets[b * U_ + u];
                lpl[(b * U_ + u) * T_ + t] = Es[tgt] + Drow[tgt] - lse;
            }
        }
    }
}

// ---------------- Kernel 3: RNN-T alpha DP, anti-diagonal wavefront.
// One block per batch; lane u owns column u; 304 serial diagonal steps.
__global__ __launch_bounds__(256) void dp_kernel(
    const float* __restrict__ lpb, const float* __restrict__ lpl,
    const int* __restrict__ tlen, const int* __restrict__ ulen,
    float* __restrict__ out)
{
    __shared__ __half slpb[(U_ + 1) * T_];   // 25088 B
    __shared__ __half slpl[U_ * T_];         // 24576 B
    const int b = blockIdx.x;
    const int tid = threadIdx.x;

    for (int i = tid; i < (U_ + 1) * T_; i += 256)
        slpb[i] = __float2half(lpb[(size_t)b * (U_ + 1) * T_ + i]);
    for (int i = tid; i < U_ * T_; i += 256)
        slpl[i] = __float2half(lpl[(size_t)b * U_ * T_ + i]);
    __syncthreads();
    if (tid >= 64) return;

    const int u = tid;
    const int TL = tlen[b], UL = ulen[b];
    float myval = 0.f;
    float result = 0.f;
    for (int d = 0; d <= (T_ - 1) + U_; ++d) {
        float nb = __shfl_up(myval, 1);
        int t = d - u;
        if (u <= U_ && t >= 0 && t < T_) {
            float v;
            if (t == 0) {
                v = (u == 0) ? 0.f : nb + __half2float(slpl[(u - 1) * T_ + 0]);
            } else if (u == 0) {
                v = myval + __half2float(slpb[0 * T_ + (t - 1)]);
            } else {
                float x = myval + __half2float(slpb[u * T_ + (t - 1)]);
                float y = nb + __half2float(slpl[(u - 1) * T_ + t]);
                float mx = fmaxf(x, y);
                float mn = fminf(x, y);
                v = mx + log1pf(__expf(mn - mx));
            }
            myval = v;
            if (t == TL - 1 && u == UL)
                result = -(myval + __half2float(slpb[u * T_ + t]));
        }
    }
    if (u == UL) out[b] = result;
}

extern "C" void kernel_launch(void* const* d_in, const int* in_sizes, int n_in,
                              void* d_out, int out_size, void* d_ws, size_t ws_size,
                              hipStream_t stream) {
    const float* enc     = (const float*)d_in[0];   // B,T,H
    const float* dec     = (const float*)d_in[1];   // B,U+1,H
    const float* W       = (const float*)d_in[2];   // V,H
    const float* bias    = (const float*)d_in[3];   // V
    const int*   targets = (const int*)d_in[4];     // B,U
    const int*   tlen    = (const int*)d_in[5];     // B
    const int*   ulen    = (const int*)d_in[6];     // B
    float* out = (float*)d_out;

    float* ws = (float*)d_ws;
    float* E   = ws;                                  // B*T*V      = 1048576
    float* D   = E + (size_t)GM_ENC * V_;             // B*(U+1)*V  = 200704
    float* lpb = D + (size_t)B_ * (U_ + 1) * V_;      // B*(U+1)*T  = 50176
    float* lpl = lpb + (size_t)B_ * (U_ + 1) * T_;    // B*U*T      = 49152

    dim3 gblock(256);
    dim3 ggrid(V_ / 64, (GM + 63) / 64);              // (16, 20)
    gemm_kernel<<<ggrid, gblock, 0, stream>>>(enc, dec, W, bias, E, D);

    lse_kernel<<<dim3(B_ * T_), dim3(256), 0, stream>>>(E, D, targets, lpb, lpl);

    dp_kernel<<<dim3(B_), dim3(256), 0, stream>>>(lpb, lpl, tlen, ulen, out);
}

// Round 2
// 91.768 us; speedup vs baseline: 2.0705x; 2.0705x over previous
//
#include <hip/hip_runtime.h>
#include <hip/hip_fp16.h>
#include <math.h>

#define B_ 4
#define T_ 256
#define U_ 48
#define H_ 512
#define V_ 1024
#define BLANK_ (V_-1)

#define GM 1220        // B*T + B*(U+1)
#define GM_ENC 1024    // B*T

#define NEGINF (-__builtin_inff())
#define INVLN2 1.4426950408889634f
#define LN2F   0.6931471805599453f

// ---------------- Kernel 1: C = [enc;dec] @ W^T  (+bias for enc rows)
__global__ __launch_bounds__(256) void gemm_kernel(
    const float* __restrict__ enc, const float* __restrict__ dec,
    const float* __restrict__ W, const float* __restrict__ bias,
    float* __restrict__ E, float* __restrict__ D)
{
    __shared__ float As[16][68];
    __shared__ float Bs[16][68];
    const int tid = threadIdx.x;
    const int tx = tid & 15, ty = tid >> 4;
    const int bx = blockIdx.x, by = blockIdx.y;
    const int row0 = by * 64, col0 = bx * 64;

    float acc[4][4] = {};
    const int lrow = tid >> 2;
    const int lk   = (tid & 3) * 4;

    for (int k0 = 0; k0 < H_; k0 += 16) {
        int gr = row0 + lrow;
        float4 av = make_float4(0.f, 0.f, 0.f, 0.f);
        if (gr < GM) {
            const float* src = (gr < GM_ENC) ? (enc + (size_t)gr * H_)
                                             : (dec + (size_t)(gr - GM_ENC) * H_);
            av = *(const float4*)(src + k0 + lk);
        }
        float4 bv = *(const float4*)(W + (size_t)(col0 + lrow) * H_ + k0 + lk);
        __syncthreads();
        As[lk + 0][lrow] = av.x; As[lk + 1][lrow] = av.y;
        As[lk + 2][lrow] = av.z; As[lk + 3][lrow] = av.w;
        Bs[lk + 0][lrow] = bv.x; Bs[lk + 1][lrow] = bv.y;
        Bs[lk + 2][lrow] = bv.z; Bs[lk + 3][lrow] = bv.w;
        __syncthreads();
        #pragma unroll
        for (int k = 0; k < 16; ++k) {
            float4 a = *(const float4*)&As[k][ty * 4];
            float4 b = *(const float4*)&Bs[k][tx * 4];
            float ar[4] = {a.x, a.y, a.z, a.w};
            float br[4] = {b.x, b.y, b.z, b.w};
            #pragma unroll
            for (int i = 0; i < 4; ++i)
                #pragma unroll
                for (int j = 0; j < 4; ++j)
                    acc[i][j] += ar[i] * br[j];
        }
    }
    #pragma unroll
    for (int i = 0; i < 4; ++i) {
        int r = row0 + ty * 4 + i;
        if (r >= GM) continue;
        int c = col0 + tx * 4;
        if (r < GM_ENC) {
            float4 bb = *(const float4*)(bias + c);
            float4 o = make_float4(acc[i][0] + bb.x, acc[i][1] + bb.y,
                                   acc[i][2] + bb.z, acc[i][3] + bb.w);
            *(float4*)(E + (size_t)r * V_ + c) = o;
        } else {
            float4 o = make_float4(acc[i][0], acc[i][1], acc[i][2], acc[i][3]);
            *(float4*)(D + (size_t)(r - GM_ENC) * V_ + c) = o;
        }
    }
}

// ---------------- Kernel 2: per (b,t): LSE over V of E[b,t,:]+D[b,u,:]
// writes lp_blank/lp_label transposed [b][u][t], fp16, pre-scaled by 1/ln2
__global__ __launch_bounds__(256) void lse_kernel(
    const float* __restrict__ E, const float* __restrict__ D,
    const int* __restrict__ targets,
    __half* __restrict__ lpb, __half* __restrict__ lpl)
{
    __shared__ float Es[V_];
    const int bt = blockIdx.x;
    const int b = bt >> 8, t = bt & 255;
    const int tid = threadIdx.x;

    *(float4*)(Es + tid * 4) = *(const float4*)(E + (size_t)bt * V_ + tid * 4);
    __syncthreads();

    const int wave = tid >> 6, lane = tid & 63;
    for (int u = wave; u <= U_; u += 4) {
        const float* Drow = D + (size_t)(b * (U_ + 1) + u) * V_;
        float vals[16];
        float m = -INFINITY;
        #pragma unroll
        for (int j = 0; j < 16; ++j) {
            int v = j * 64 + lane;
            vals[j] = Es[v] + Drow[v];
            m = fmaxf(m, vals[j]);
        }
        #pragma unroll
        for (int off = 32; off; off >>= 1)
            m = fmaxf(m, __shfl_xor(m, off));
        float s = 0.f;
        #pragma unroll
        for (int j = 0; j < 16; ++j)
            s += __expf(vals[j] - m);
        #pragma unroll
        for (int off = 32; off; off >>= 1)
            s += __shfl_xor(s, off);
        float lse = m + __logf(s);
        if (lane == 0) {
            lpb[(b * (U_ + 1) + u) * T_ + t] =
                __float2half((Es[BLANK_] + Drow[BLANK_] - lse) * INVLN2);
            if (u < U_) {
                int tgt = targets[b * U_ + u];
                lpl[(b * U_ + u) * T_ + t] =
                    __float2half((Es[tgt] + Drow[tgt] - lse) * INVLN2);
            }
        }
    }
}

// logaddexp in log2 domain: two native transcendentals, ~6-op dep chain
__device__ __forceinline__ float lad2(float x, float y) {
    float mx = fmaxf(x, y);
    float mn = fminf(x, y);
    return mx + __builtin_amdgcn_logf(1.0f + __builtin_amdgcn_exp2f(mn - mx));
}

// ---------------- Kernel 3: RNN-T alpha DP.
// Lane l owns t in [4l, 4l+3]; superstep s computes u = s - l (t-block wavefront).
// 112 supersteps, 1 shfl + 4 cells each; LDS payloads software-pipelined 1 deep.
__global__ __launch_bounds__(256) void dp_kernel(
    const __half* __restrict__ lpb, const __half* __restrict__ lpl,
    const int* __restrict__ tlen, const int* __restrict__ ulen,
    float* __restrict__ out)
{
    __shared__ __half slpb[(U_ + 1) * T_];   // 25088 B, log2-domain fp16
    __shared__ __half slpl[U_ * T_];         // 24576 B
    const int b = blockIdx.x;
    const int tid = threadIdx.x;
    {
        const uint2* gb = (const uint2*)(lpb + (size_t)b * (U_ + 1) * T_);
        uint2* sb = (uint2*)slpb;
        for (int i = tid; i < (U_ + 1) * T_ / 4; i += 256) sb[i] = gb[i];
        const uint2* gl = (const uint2*)(lpl + (size_t)b * U_ * T_);
        uint2* sl = (uint2*)slpl;
        for (int i = tid; i < U_ * T_ / 4; i += 256) sl[i] = gl[i];
    }
    __syncthreads();
    if (tid >= 64) return;

    const int l = tid;
    const int t0 = 4 * l;
    const int TL = tlen[b], UL = ulen[b];
    const int lt = (TL - 1) >> 2;
    const int smax = lt + UL;

    float pu0 = NEGINF, pu1 = NEGINF, pu2 = NEGINF, pu3 = NEGINF; // alpha[t][u-1]
    float a3 = NEGINF;                                            // lane's last cell
    float r0 = 0.f, r1 = 0.f, r2 = 0.f, r3 = 0.f;

    // pipeline payloads (raw halfs; convert at use, one superstep later)
    uint2 bq, lq; __half bx;
    auto issue = [&](int ss, uint2& obq, uint2& olq, __half& obx) {
        int uu = ss - l;
        int ub  = min(max(uu, 0), U_);
        int ul2 = min(max(uu - 1, 0), U_ - 1);
        obq = *(const uint2*)(slpb + ub * T_ + t0);     // lpb2[u][t0..t0+3]
        olq = *(const uint2*)(slpl + ul2 * T_ + t0);    // lpl2[u-1][t0..t0+3]
        obx = slpb[ub * T_ + (t0 > 0 ? t0 - 1 : 0)];    // lpb2[u][t0-1]
    };
    issue(0, bq, lq, bx);

    for (int s = 0; s <= smax; ++s) {
        // convert current payload (loads issued a full superstep ago)
        const __half2* bh = (const __half2*)&bq;
        float2 b01 = __half22float2(bh[0]);
        float2 b23 = __half22float2(bh[1]);
        const __half2* lh = (const __half2*)&lq;
        float2 l01 = __half22float2(lh[0]);
        float2 l23 = __half22float2(lh[1]);
        float B0 = __half2float(bx);
        float B1 = b01.x, B2 = b01.y, B3 = b23.x;
        float L0 = l01.x, L1 = l01.y, L2 = l23.x, L3 = l23.y;

        // issue next payload (off the dependency chain)
        uint2 nbq, nlq; __half nbx;
        issue(s + 1, nbq, nlq, nbx);

        float bound = __shfl_up(a3, 1);   // alpha[t0-1][u] from lane l-1
        int u = s - l;
        if (u >= 0 && u <= U_) {
            if (l == 0) bound = NEGINF;
            float y0 = pu0 + L0, y1 = pu1 + L1, y2 = pu2 + L2, y3 = pu3 + L3;
            float a0 = lad2(bound + B0, y0);
            if (l == 0 && u == 0) a0 = 0.f;          // alpha[0][0], kills the NaN
            float a1 = lad2(a0 + B1, y1);
            float a2 = lad2(a1 + B2, y2);
            float a3n = lad2(a2 + B3, y3);
            pu0 = a0; pu1 = a1; pu2 = a2; pu3 = a3n;
            a3 = a3n;
            if (u == UL && l == lt) { r0 = a0; r1 = a1; r2 = a2; r3 = a3n; }
        }
        bq = nbq; lq = nlq; bx = nbx;
    }

    if (l == lt) {
        int j = (TL - 1) & 3;
        float a = (j == 0) ? r0 : (j == 1) ? r1 : (j == 2) ? r2 : r3;
        float lb = __half2float(slpb[UL * T_ + (TL - 1)]);
        out[b] = -(a + lb) * LN2F;
    }
}

extern "C" void kernel_launch(void* const* d_in, const int* in_sizes, int n_in,
                              void* d_out, int out_size, void* d_ws, size_t ws_size,
                              hipStream_t stream) {
    const float* enc     = (const float*)d_in[0];
    const float* dec     = (const float*)d_in[1];
    const float* W       = (const float*)d_in[2];
    const float* bias    = (const float*)d_in[3];
    const int*   targets = (const int*)d_in[4];
    const int*   tlen    = (const int*)d_in[5];
    const int*   ulen    = (const int*)d_in[6];
    float* out = (float*)d_out;

    float* ws = (float*)d_ws;
    float* E   = ws;                                  // B*T*V fp32
    float* D   = E + (size_t)GM_ENC * V_;             // B*(U+1)*V fp32
    __half* lpb = (__half*)(D + (size_t)B_ * (U_ + 1) * V_);   // fp16 log2
    __half* lpl = lpb + (size_t)B_ * (U_ + 1) * T_;            // fp16 log2

    dim3 gblock(256);
    dim3 ggrid(V_ / 64, (GM + 63) / 64);
    gemm_kernel<<<ggrid, gblock, 0, stream>>>(enc, dec, W, bias, E, D);

    lse_kernel<<<dim3(B_ * T_), dim3(256), 0, stream>>>(E, D, targets, lpb, lpl);

    dp_kernel<<<dim3(B_), dim3(256), 0, stream>>>(lpb, lpl, tlen, ulen, out);
}

// Round 3
// 77.412 us; speedup vs baseline: 2.4544x; 1.1854x over previous
//
#include <hip/hip_runtime.h>
#include <hip/hip_fp16.h>
#include <math.h>

#define B_ 4
#define T_ 256
#define U_ 48
#define H_ 512
#define V_ 1024
#define BLANK_ (V_-1)

#define GM 1220        // B*T + B*(U+1)
#define GM_ENC 1024    // B*T
#define APAD 1280      // GM padded to 64

#define NEGINF (-__builtin_inff())
#define INVLN2 1.4426950408889634f
#define LN2F   0.6931471805599453f

typedef __attribute__((ext_vector_type(8))) short short8;
typedef __attribute__((ext_vector_type(4))) float f32x4;

__device__ __forceinline__ unsigned short f2bf(float x) {
    union { float f; unsigned int u; } c; c.f = x;
    unsigned int r = c.u + 0x7FFF + ((c.u >> 16) & 1);   // RNE
    return (unsigned short)(r >> 16);
}

// ---------------- Kernel 0: fp32 -> bf16 staging for A=[enc;dec] (padded) and W
__global__ __launch_bounds__(256) void convert_kernel(
    const float* __restrict__ enc, const float* __restrict__ dec,
    const float* __restrict__ W,
    unsigned short* __restrict__ Abf, unsigned short* __restrict__ Wbf)
{
    const int ATOT = APAD * H_ / 8;   // 81920 chunks of 8
    const int WTOT = V_ * H_ / 8;     // 65536
    int i = blockIdx.x * 256 + threadIdx.x;
    float4 v0 = make_float4(0.f,0.f,0.f,0.f), v1 = v0;
    unsigned short* dst;
    if (i < ATOT) {
        int base = i * 8;
        int row = base >> 9;          // /H
        int k   = base & (H_ - 1);
        if (row < GM_ENC) {
            const float* s = enc + ((size_t)row << 9) + k;
            v0 = *(const float4*)s; v1 = *(const float4*)(s + 4);
        } else if (row < GM) {
            const float* s = dec + ((size_t)(row - GM_ENC) << 9) + k;
            v0 = *(const float4*)s; v1 = *(const float4*)(s + 4);
        }
        dst = Abf + base;
    } else if (i < ATOT + WTOT) {
        int base = (i - ATOT) * 8;
        const float* s = W + base;
        v0 = *(const float4*)s; v1 = *(const float4*)(s + 4);
        dst = Wbf + base;
    } else return;
    unsigned short h[8] = { f2bf(v0.x), f2bf(v0.y), f2bf(v0.z), f2bf(v0.w),
                            f2bf(v1.x), f2bf(v1.y), f2bf(v1.z), f2bf(v1.w) };
    *(uint4*)dst = *(const uint4*)h;
}

// ---------------- Kernel 1: E/D = A @ W^T via bf16 MFMA (64x64x64 tiles)
__global__ __launch_bounds__(256) void gemm_kernel(
    const unsigned short* __restrict__ Abf, const unsigned short* __restrict__ Wbf,
    const float* __restrict__ bias,
    float* __restrict__ E, float* __restrict__ D)
{
    __shared__ __attribute__((aligned(16))) unsigned short As[64 * 64]; // XOR-swizzled
    __shared__ __attribute__((aligned(16))) unsigned short Bs[64 * 64];
    const int tid  = threadIdx.x;
    const int lane = tid & 63, wave = tid >> 6;
    const int wm = wave >> 1, wn = wave & 1;
    const int row0 = blockIdx.y * 64, col0 = blockIdx.x * 64;

    f32x4 acc[2][2];
    #pragma unroll
    for (int mi = 0; mi < 2; ++mi)
        #pragma unroll
        for (int ni = 0; ni < 2; ++ni)
            acc[mi][ni] = (f32x4){0.f, 0.f, 0.f, 0.f};

    for (int k0 = 0; k0 < H_; k0 += 64) {
        __syncthreads();
        #pragma unroll
        for (int c = 0; c < 2; ++c) {
            int off  = (tid + 256 * c) * 16;       // linear byte offset in 8KB tile
            int row  = off >> 7;                   // /128B
            int colb = off & 127;
            int sw   = colb ^ ((row & 7) << 4);
            short8 av = *(const short8*)((const char*)Abf + (size_t)(row0 + row) * (H_*2) + k0*2 + colb);
            *(short8*)((char*)As + row * 128 + sw) = av;
            short8 bv = *(const short8*)((const char*)Wbf + (size_t)(col0 + row) * (H_*2) + k0*2 + colb);
            *(short8*)((char*)Bs + row * 128 + sw) = bv;
        }
        __syncthreads();
        #pragma unroll
        for (int kk = 0; kk < 2; ++kk) {
            short8 a[2], b[2];
            const int cb = kk * 64 + (lane >> 4) * 16;
            #pragma unroll
            for (int mi = 0; mi < 2; ++mi) {
                int r = wm * 32 + mi * 16 + (lane & 15);
                a[mi] = *(const short8*)((const char*)As + r * 128 + (cb ^ ((r & 7) << 4)));
            }
            #pragma unroll
            for (int ni = 0; ni < 2; ++ni) {
                int r = wn * 32 + ni * 16 + (lane & 15);
                b[ni] = *(const short8*)((const char*)Bs + r * 128 + (cb ^ ((r & 7) << 4)));
            }
            #pragma unroll
            for (int mi = 0; mi < 2; ++mi)
                #pragma unroll
                for (int ni = 0; ni < 2; ++ni)
                    asm("v_mfma_f32_16x16x32_bf16 %0, %1, %2, %0"
                        : "+v"(acc[mi][ni]) : "v"(a[mi]), "v"(b[ni]));
        }
    }
    // epilogue: C/D layout col=lane&15, row=(lane>>4)*4+j  [m89-verified]
    #pragma unroll
    for (int ni = 0; ni < 2; ++ni) {
        int col = col0 + wn * 32 + ni * 16 + (lane & 15);
        float bb = bias[col];
        #pragma unroll
        for (int mi = 0; mi < 2; ++mi) {
            #pragma unroll
            for (int j = 0; j < 4; ++j) {
                int gr = row0 + wm * 32 + mi * 16 + (lane >> 4) * 4 + j;
                float v = acc[mi][ni][j];
                if (gr < GM_ENC)      E[(size_t)gr * V_ + col] = v + bb;
                else if (gr < GM)     D[(size_t)(gr - GM_ENC) * V_ + col] = v;
            }
        }
    }
}

// ---------------- Kernel 2: per (b,t): LSE over V of E[b,t,:]+D[b,u,:]
// writes lp_blank/lp_label transposed [b][u][t], fp16, pre-scaled by 1/ln2
__global__ __launch_bounds__(256) void lse_kernel(
    const float* __restrict__ E, const float* __restrict__ D,
    const int* __restrict__ targets,
    __half* __restrict__ lpb, __half* __restrict__ lpl)
{
    __shared__ float Es[V_];
    const int bt = blockIdx.x;
    const int b = bt >> 8, t = bt & 255;
    const int tid = threadIdx.x;

    *(float4*)(Es + tid * 4) = *(const float4*)(E + (size_t)bt * V_ + tid * 4);
    __syncthreads();

    const int wave = tid >> 6, lane = tid & 63;
    for (int u = wave; u <= U_; u += 4) {
        const float* Drow = D + (size_t)(b * (U_ + 1) + u) * V_;
        float4 vs[4];
        float m = -INFINITY;
        #pragma unroll
        for (int j = 0; j < 4; ++j) {
            float4 ev = *(const float4*)(Es + j * 256 + lane * 4);
            float4 dv = *(const float4*)(Drow + j * 256 + lane * 4);
            vs[j].x = ev.x + dv.x; vs[j].y = ev.y + dv.y;
            vs[j].z = ev.z + dv.z; vs[j].w = ev.w + dv.w;
            m = fmaxf(m, fmaxf(fmaxf(vs[j].x, vs[j].y), fmaxf(vs[j].z, vs[j].w)));
        }
        #pragma unroll
        for (int off = 32; off; off >>= 1)
            m = fmaxf(m, __shfl_xor(m, off));
        float s = 0.f;
        #pragma unroll
        for (int j = 0; j < 4; ++j)
            s += __expf(vs[j].x - m) + __expf(vs[j].y - m)
               + __expf(vs[j].z - m) + __expf(vs[j].w - m);
        #pragma unroll
        for (int off = 32; off; off >>= 1)
            s += __shfl_xor(s, off);
        float lse = m + __logf(s);
        if (lane == 0) {
            lpb[(b * (U_ + 1) + u) * T_ + t] =
                __float2half((Es[BLANK_] + Drow[BLANK_] - lse) * INVLN2);
            if (u < U_) {
                int tgt = targets[b * U_ + u];
                lpl[(b * U_ + u) * T_ + t] =
                    __float2half((Es[tgt] + Drow[tgt] - lse) * INVLN2);
            }
        }
    }
}

// logaddexp in log2 domain
__device__ __forceinline__ float lad2(float x, float y) {
    float mx = fmaxf(x, y);
    float mn = fminf(x, y);
    return mx + __builtin_amdgcn_logf(1.0f + __builtin_amdgcn_exp2f(mn - mx));
}

// ---------------- Kernel 3: RNN-T alpha DP (t-block wavefront, pipelined LDS)
__global__ __launch_bounds__(256) void dp_kernel(
    const __half* __restrict__ lpb, const __half* __restrict__ lpl,
    const int* __restrict__ tlen, const int* __restrict__ ulen,
    float* __restrict__ out)
{
    __shared__ __half slpb[(U_ + 1) * T_];
    __shared__ __half slpl[U_ * T_];
    const int b = blockIdx.x;
    const int tid = threadIdx.x;
    {
        const uint2* gb = (const uint2*)(lpb + (size_t)b * (U_ + 1) * T_);
        uint2* sb = (uint2*)slpb;
        for (int i = tid; i < (U_ + 1) * T_ / 4; i += 256) sb[i] = gb[i];
        const uint2* gl = (const uint2*)(lpl + (size_t)b * U_ * T_);
        uint2* sl = (uint2*)slpl;
        for (int i = tid; i < U_ * T_ / 4; i += 256) sl[i] = gl[i];
    }
    __syncthreads();
    if (tid >= 64) return;

    const int l = tid;
    const int t0 = 4 * l;
    const int TL = tlen[b], UL = ulen[b];
    const int lt = (TL - 1) >> 2;
    const int smax = lt + UL;

    float pu0 = NEGINF, pu1 = NEGINF, pu2 = NEGINF, pu3 = NEGINF;
    float a3 = NEGINF;
    float r0 = 0.f, r1 = 0.f, r2 = 0.f, r3 = 0.f;

    uint2 bq, lq; __half bx;
    auto issue = [&](int ss, uint2& obq, uint2& olq, __half& obx) {
        int uu = ss - l;
        int ub  = min(max(uu, 0), U_);
        int ul2 = min(max(uu - 1, 0), U_ - 1);
        obq = *(const uint2*)(slpb + ub * T_ + t0);
        olq = *(const uint2*)(slpl + ul2 * T_ + t0);
        obx = slpb[ub * T_ + (t0 > 0 ? t0 - 1 : 0)];
    };
    issue(0, bq, lq, bx);

    for (int s = 0; s <= smax; ++s) {
        const __half2* bh = (const __half2*)&bq;
        float2 b01 = __half22float2(bh[0]);
        float2 b23 = __half22float2(bh[1]);
        const __half2* lh = (const __half2*)&lq;
        float2 l01 = __half22float2(lh[0]);
        float2 l23 = __half22float2(lh[1]);
        float B0 = __half2float(bx);
        float B1 = b01.x, B2 = b01.y, B3 = b23.x;
        float L0 = l01.x, L1 = l01.y, L2 = l23.x, L3 = l23.y;

        uint2 nbq, nlq; __half nbx;
        issue(s + 1, nbq, nlq, nbx);

        float bound = __shfl_up(a3, 1);
        int u = s - l;
        if (u >= 0 && u <= U_) {
            if (l == 0) bound = NEGINF;
            float y0 = pu0 + L0, y1 = pu1 + L1, y2 = pu2 + L2, y3 = pu3 + L3;
            float a0 = lad2(bound + B0, y0);
            if (l == 0 && u == 0) a0 = 0.f;
            float a1 = lad2(a0 + B1, y1);
            float a2 = lad2(a1 + B2, y2);
            float a3n = lad2(a2 + B3, y3);
            pu0 = a0; pu1 = a1; pu2 = a2; pu3 = a3n;
            a3 = a3n;
            if (u == UL && l == lt) { r0 = a0; r1 = a1; r2 = a2; r3 = a3n; }
        }
        bq = nbq; lq = nlq; bx = nbx;
    }

    if (l == lt) {
        int j = (TL - 1) & 3;
        float a = (j == 0) ? r0 : (j == 1) ? r1 : (j == 2) ? r2 : r3;
        float lb = __half2float(slpb[UL * T_ + (TL - 1)]);
        out[b] = -(a + lb) * LN2F;
    }
}

extern "C" void kernel_launch(void* const* d_in, const int* in_sizes, int n_in,
                              void* d_out, int out_size, void* d_ws, size_t ws_size,
                              hipStream_t stream) {
    const float* enc     = (const float*)d_in[0];
    const float* dec     = (const float*)d_in[1];
    const float* W       = (const float*)d_in[2];
    const float* bias    = (const float*)d_in[3];
    const int*   targets = (const int*)d_in[4];
    const int*   tlen    = (const int*)d_in[5];
    const int*   ulen    = (const int*)d_in[6];
    float* out = (float*)d_out;

    float* ws = (float*)d_ws;
    float* E   = ws;                                           // GM_ENC*V fp32
    float* D   = E + (size_t)GM_ENC * V_;                      // B*(U+1)*V fp32
    __half* lpb = (__half*)(D + (size_t)B_ * (U_ + 1) * V_);   // fp16 log2
    __half* lpl = lpb + (size_t)B_ * (U_ + 1) * T_;
    unsigned short* Abf = (unsigned short*)(lpl + (size_t)B_ * U_ * T_);
    unsigned short* Wbf = Abf + (size_t)APAD * H_;

    convert_kernel<<<dim3((APAD*H_/8 + V_*H_/8 + 255)/256), dim3(256), 0, stream>>>(
        enc, dec, W, Abf, Wbf);

    gemm_kernel<<<dim3(V_/64, APAD/64), dim3(256), 0, stream>>>(Abf, Wbf, bias, E, D);

    lse_kernel<<<dim3(B_ * T_), dim3(256), 0, stream>>>(E, D, targets, lpb, lpl);

    dp_kernel<<<dim3(B_), dim3(256), 0, stream>>>(lpb, lpl, tlen, ulen, out);
}

// Round 4
// 63.027 us; speedup vs baseline: 3.0146x; 1.2283x over previous
//
#include <hip/hip_runtime.h>
#include <hip/hip_fp16.h>
#include <math.h>

#define B_ 4
#define T_ 256
#define U_ 48
#define H_ 512
#define V_ 1024
#define BLANK_ (V_-1)

#define GM 1220        // B*T + B*(U+1)
#define GM_ENC 1024    // B*T
#define APAD 1280

#define NEGINF (-__builtin_inff())
#define INVLN2 1.4426950408889634f
#define LN2F   0.6931471805599453f

typedef __attribute__((ext_vector_type(8))) short short8;
typedef __attribute__((ext_vector_type(4))) float f32x4;

__device__ __forceinline__ unsigned short f2bf(float x) {
    union { float f; unsigned int u; } c; c.f = x;
    unsigned int r = c.u + 0x7FFF + ((c.u >> 16) & 1);   // RNE
    return (unsigned short)(r >> 16);
}
__device__ __forceinline__ float bf2f(unsigned short u) {
    union { unsigned int i; float f; } c; c.i = ((unsigned int)u) << 16; return c.f;
}
__device__ __forceinline__ unsigned int cvt_pk_bf16(float lo, float hi) {
    unsigned int r;
    asm("v_cvt_pk_bf16_f32 %0, %1, %2" : "=v"(r) : "v"(lo), "v"(hi));
    return r;
}

// ---------------- K1: Pexp = exp2(([enc;dec]@W^T + bias)·log2e) in bf16
// fused fp32->bf16 panel convert; 64x64x64 MFMA tiles; rows 0..1023 = enc(+bias),
// rows 1024..1219 = dec (no bias).
__global__ __launch_bounds__(256) void gemm1_kernel(
    const float* __restrict__ enc, const float* __restrict__ dec,
    const float* __restrict__ W, const float* __restrict__ bias,
    unsigned short* __restrict__ Pexp)
{
    __shared__ __attribute__((aligned(16))) unsigned short As[64 * 64];
    __shared__ __attribute__((aligned(16))) unsigned short Bs[64 * 64];
    const int tid  = threadIdx.x;
    const int lane = tid & 63, wave = tid >> 6;
    const int wm = wave >> 1, wn = wave & 1;
    const int row0 = blockIdx.y * 64, col0 = blockIdx.x * 64;

    const int srow = tid >> 2;          // staging: row 0..63
    const int scg  = (tid & 3) * 16;    // col group (elements)

    f32x4 acc[2][2];
    #pragma unroll
    for (int mi = 0; mi < 2; ++mi)
        #pragma unroll
        for (int ni = 0; ni < 2; ++ni)
            acc[mi][ni] = (f32x4){0.f, 0.f, 0.f, 0.f};

    for (int k0 = 0; k0 < H_; k0 += 64) {
        __syncthreads();
        // ---- stage A (fp32 -> bf16)
        {
            int gr = row0 + srow;
            float4 a0, a1, a2, a3;
            a0 = a1 = a2 = a3 = make_float4(0.f, 0.f, 0.f, 0.f);
            if (gr < GM) {
                const float* s = (gr < GM_ENC)
                    ? enc + (size_t)gr * H_ + k0 + scg
                    : dec + (size_t)(gr - GM_ENC) * H_ + k0 + scg;
                a0 = *(const float4*)s; a1 = *(const float4*)(s + 4);
                a2 = *(const float4*)(s + 8); a3 = *(const float4*)(s + 12);
            }
            uint4 w0 = { cvt_pk_bf16(a0.x, a0.y), cvt_pk_bf16(a0.z, a0.w),
                         cvt_pk_bf16(a1.x, a1.y), cvt_pk_bf16(a1.z, a1.w) };
            uint4 w1 = { cvt_pk_bf16(a2.x, a2.y), cvt_pk_bf16(a2.z, a2.w),
                         cvt_pk_bf16(a3.x, a3.y), cvt_pk_bf16(a3.z, a3.w) };
            int colb = scg * 2;
            int sw0 = (colb)      ^ ((srow & 7) << 4);
            int sw1 = (colb + 16) ^ ((srow & 7) << 4);
            *(uint4*)((char*)As + srow * 128 + sw0) = w0;
            *(uint4*)((char*)As + srow * 128 + sw1) = w1;
        }
        // ---- stage B (W rows, fp32 -> bf16)
        {
            const float* s = W + (size_t)(col0 + srow) * H_ + k0 + scg;
            float4 b0 = *(const float4*)s, b1 = *(const float4*)(s + 4);
            float4 b2 = *(const float4*)(s + 8), b3 = *(const float4*)(s + 12);
            uint4 w0 = { cvt_pk_bf16(b0.x, b0.y), cvt_pk_bf16(b0.z, b0.w),
                         cvt_pk_bf16(b1.x, b1.y), cvt_pk_bf16(b1.z, b1.w) };
            uint4 w1 = { cvt_pk_bf16(b2.x, b2.y), cvt_pk_bf16(b2.z, b2.w),
                         cvt_pk_bf16(b3.x, b3.y), cvt_pk_bf16(b3.z, b3.w) };
            int colb = scg * 2;
            int sw0 = (colb)      ^ ((srow & 7) << 4);
            int sw1 = (colb + 16) ^ ((srow & 7) << 4);
            *(uint4*)((char*)Bs + srow * 128 + sw0) = w0;
            *(uint4*)((char*)Bs + srow * 128 + sw1) = w1;
        }
        __syncthreads();
        #pragma unroll
        for (int kk = 0; kk < 2; ++kk) {
            short8 a[2], b[2];
            const int cb = kk * 64 + (lane >> 4) * 16;
            #pragma unroll
            for (int mi = 0; mi < 2; ++mi) {
                int r = wm * 32 + mi * 16 + (lane & 15);
                a[mi] = *(const short8*)((const char*)As + r * 128 + (cb ^ ((r & 7) << 4)));
            }
            #pragma unroll
            for (int ni = 0; ni < 2; ++ni) {
                int r = wn * 32 + ni * 16 + (lane & 15);
                b[ni] = *(const short8*)((const char*)Bs + r * 128 + (cb ^ ((r & 7) << 4)));
            }
            #pragma unroll
            for (int mi = 0; mi < 2; ++mi)
                #pragma unroll
                for (int ni = 0; ni < 2; ++ni)
                    asm("v_mfma_f32_16x16x32_bf16 %0, %1, %2, %0"
                        : "+v"(acc[mi][ni]) : "v"(a[mi]), "v"(b[ni]));
        }
    }
    // epilogue: C/D layout col=lane&15, row=(lane>>4)*4+j
    #pragma unroll
    for (int ni = 0; ni < 2; ++ni) {
        int col = col0 + wn * 32 + ni * 16 + (lane & 15);
        float bb = bias[col];
        #pragma unroll
        for (int mi = 0; mi < 2; ++mi) {
            #pragma unroll
            for (int j = 0; j < 4; ++j) {
                int gr = row0 + wm * 32 + mi * 16 + (lane >> 4) * 4 + j;
                if (gr >= GM) continue;
                float v = acc[mi][ni][j] + (gr < GM_ENC ? bb : 0.f);
                float p = __builtin_amdgcn_exp2f(v * INVLN2);
                Pexp[(size_t)gr * V_ + col] = f2bf(p);
            }
        }
    }
}

// ---------------- K2: denom[bt,u] = <Pexp_enc[bt,:], Pexp_dec[bu,:]> via MFMA,
// epilogue writes lpb/lpl (log2-domain fp16, transposed [b][u][t]).
__global__ __launch_bounds__(256) void gemm2_kernel(
    const unsigned short* __restrict__ Pexp, const int* __restrict__ targets,
    __half* __restrict__ lpb, __half* __restrict__ lpl)
{
    __shared__ __attribute__((aligned(16))) unsigned short As[64 * 64];
    __shared__ __attribute__((aligned(16))) unsigned short Bs[64 * 64];
    __shared__ float rowb2[64];   // log2 Pexp[enc row][BLANK]
    __shared__ float colb2[64];   // log2 Pexp[dec row u][BLANK]
    __shared__ float pdt2[64];    // log2 Pexp[dec row u][tgt[u]]
    __shared__ int   tgtc[64];
    const int tid  = threadIdx.x;
    const int lane = tid & 63, wave = tid >> 6;
    const int wm = wave >> 1, wn = wave & 1;
    const int mt = blockIdx.x, b = blockIdx.y;

    if (tid < 64) {
        size_t grow = (size_t)(b * 256 + mt * 64 + tid);
        rowb2[tid] = __builtin_amdgcn_logf(bf2f(Pexp[grow * V_ + BLANK_]));
        if (tid <= U_) {
            size_t drow = (size_t)(GM_ENC + b * (U_ + 1) + tid);
            colb2[tid] = __builtin_amdgcn_logf(bf2f(Pexp[drow * V_ + BLANK_]));
            if (tid < U_) {
                int tg = targets[b * U_ + tid];
                tgtc[tid] = tg;
                pdt2[tid] = __builtin_amdgcn_logf(bf2f(Pexp[drow * V_ + tg]));
            }
        }
    }

    f32x4 acc[2][2];
    #pragma unroll
    for (int mi = 0; mi < 2; ++mi)
        #pragma unroll
        for (int ni = 0; ni < 2; ++ni)
            acc[mi][ni] = (f32x4){0.f, 0.f, 0.f, 0.f};

    for (int k0 = 0; k0 < V_; k0 += 64) {
        __syncthreads();
        #pragma unroll
        for (int c = 0; c < 2; ++c) {
            int off  = (tid + 256 * c) * 16;
            int row  = off >> 7;
            int colb = off & 127;
            int sw   = colb ^ ((row & 7) << 4);
            size_t arow = (size_t)(b * 256 + mt * 64 + row);
            short8 av = *(const short8*)((const char*)Pexp + arow * (V_*2) + k0*2 + colb);
            *(short8*)((char*)As + row * 128 + sw) = av;
            size_t brow = (size_t)(GM_ENC + b * (U_ + 1) + (row <= U_ ? row : U_));
            short8 bv = *(const short8*)((const char*)Pexp + brow * (V_*2) + k0*2 + colb);
            *(short8*)((char*)Bs + row * 128 + sw) = bv;
        }
        __syncthreads();
        #pragma unroll
        for (int kk = 0; kk < 2; ++kk) {
            short8 a[2], bfr[2];
            const int cb = kk * 64 + (lane >> 4) * 16;
            #pragma unroll
            for (int mi = 0; mi < 2; ++mi) {
                int r = wm * 32 + mi * 16 + (lane & 15);
                a[mi] = *(const short8*)((const char*)As + r * 128 + (cb ^ ((r & 7) << 4)));
            }
            #pragma unroll
            for (int ni = 0; ni < 2; ++ni) {
                int r = wn * 32 + ni * 16 + (lane & 15);
                bfr[ni] = *(const short8*)((const char*)Bs + r * 128 + (cb ^ ((r & 7) << 4)));
            }
            #pragma unroll
            for (int mi = 0; mi < 2; ++mi)
                #pragma unroll
                for (int ni = 0; ni < 2; ++ni)
                    asm("v_mfma_f32_16x16x32_bf16 %0, %1, %2, %0"
                        : "+v"(acc[mi][ni]) : "v"(a[mi]), "v"(bfr[ni]));
        }
    }
    // epilogue
    #pragma unroll
    for (int ni = 0; ni < 2; ++ni) {
        int u = wn * 32 + ni * 16 + (lane & 15);
        if (u > U_) continue;
        #pragma unroll
        for (int mi = 0; mi < 2; ++mi) {
            #pragma unroll
            for (int j = 0; j < 4; ++j) {
                int r = wm * 32 + mi * 16 + (lane >> 4) * 4 + j;
                int t = mt * 64 + r;
                float lse2 = __builtin_amdgcn_logf(acc[mi][ni][j]);
                lpb[(b * (U_ + 1) + u) * T_ + t] =
                    __float2half(rowb2[r] + colb2[u] - lse2);
                if (u < U_) {
                    float pe = bf2f(Pexp[(size_t)(b * 256 + t) * V_ + tgtc[u]]);
                    lpl[(b * U_ + u) * T_ + t] =
                        __float2half(__builtin_amdgcn_logf(pe) + pdt2[u] - lse2);
                }
            }
        }
    }
}

// logaddexp in log2 domain
__device__ __forceinline__ float lad2(float x, float y) {
    float mx = fmaxf(x, y);
    float mn = fminf(x, y);
    return mx + __builtin_amdgcn_logf(1.0f + __builtin_amdgcn_exp2f(mn - mx));
}

// ---------------- K3: RNN-T alpha DP (t-block wavefront, pipelined LDS)
__global__ __launch_bounds__(256) void dp_kernel(
    const __half* __restrict__ lpb, const __half* __restrict__ lpl,
    const int* __restrict__ tlen, const int* __restrict__ ulen,
    float* __restrict__ out)
{
    __shared__ __half slpb[(U_ + 1) * T_];
    __shared__ __half slpl[U_ * T_];
    const int b = blockIdx.x;
    const int tid = threadIdx.x;
    {
        const uint2* gb = (const uint2*)(lpb + (size_t)b * (U_ + 1) * T_);
        uint2* sb = (uint2*)slpb;
        for (int i = tid; i < (U_ + 1) * T_ / 4; i += 256) sb[i] = gb[i];
        const uint2* gl = (const uint2*)(lpl + (size_t)b * U_ * T_);
        uint2* sl = (uint2*)slpl;
        for (int i = tid; i < U_ * T_ / 4; i += 256) sl[i] = gl[i];
    }
    __syncthreads();
    if (tid >= 64) return;

    const int l = tid;
    const int t0 = 4 * l;
    const int TL = tlen[b], UL = ulen[b];
    const int lt = (TL - 1) >> 2;
    const int smax = lt + UL;

    float pu0 = NEGINF, pu1 = NEGINF, pu2 = NEGINF, pu3 = NEGINF;
    float a3 = NEGINF;
    float r0 = 0.f, r1 = 0.f, r2 = 0.f, r3 = 0.f;

    uint2 bq, lq; __half bx;
    auto issue = [&](int ss, uint2& obq, uint2& olq, __half& obx) {
        int uu = ss - l;
        int ub  = min(max(uu, 0), U_);
        int ul2 = min(max(uu - 1, 0), U_ - 1);
        obq = *(const uint2*)(slpb + ub * T_ + t0);
        olq = *(const uint2*)(slpl + ul2 * T_ + t0);
        obx = slpb[ub * T_ + (t0 > 0 ? t0 - 1 : 0)];
    };
    issue(0, bq, lq, bx);

    for (int s = 0; s <= smax; ++s) {
        const __half2* bh = (const __half2*)&bq;
        float2 b01 = __half22float2(bh[0]);
        float2 b23 = __half22float2(bh[1]);
        const __half2* lh = (const __half2*)&lq;
        float2 l01 = __half22float2(lh[0]);
        float2 l23 = __half22float2(lh[1]);
        float B0 = __half2float(bx);
        float B1 = b01.x, B2 = b01.y, B3 = b23.x;
        float L0 = l01.x, L1 = l01.y, L2 = l23.x, L3 = l23.y;

        uint2 nbq, nlq; __half nbx;
        issue(s + 1, nbq, nlq, nbx);

        float bound = __shfl_up(a3, 1);
        int u = s - l;
        if (u >= 0 && u <= U_) {
            if (l == 0) bound = NEGINF;
            float y0 = pu0 + L0, y1 = pu1 + L1, y2 = pu2 + L2, y3 = pu3 + L3;
            float a0 = lad2(bound + B0, y0);
            if (l == 0 && u == 0) a0 = 0.f;
            float a1 = lad2(a0 + B1, y1);
            float a2 = lad2(a1 + B2, y2);
            float a3n = lad2(a2 + B3, y3);
            pu0 = a0; pu1 = a1; pu2 = a2; pu3 = a3n;
            a3 = a3n;
            if (u == UL && l == lt) { r0 = a0; r1 = a1; r2 = a2; r3 = a3n; }
        }
        bq = nbq; lq = nlq; bx = nbx;
    }

    if (l == lt) {
        int j = (TL - 1) & 3;
        float a = (j == 0) ? r0 : (j == 1) ? r1 : (j == 2) ? r2 : r3;
        float lb = __half2float(slpb[UL * T_ + (TL - 1)]);
        out[b] = -(a + lb) * LN2F;
    }
}

extern "C" void kernel_launch(void* const* d_in, const int* in_sizes, int n_in,
                              void* d_out, int out_size, void* d_ws, size_t ws_size,
                              hipStream_t stream) {
    const float* enc     = (const float*)d_in[0];
    const float* dec     = (const float*)d_in[1];
    const float* W       = (const float*)d_in[2];
    const float* bias    = (const float*)d_in[3];
    const int*   targets = (const int*)d_in[4];
    const int*   tlen    = (const int*)d_in[5];
    const int*   ulen    = (const int*)d_in[6];
    float* out = (float*)d_out;

    unsigned short* Pexp = (unsigned short*)d_ws;          // APAD x V bf16
    __half* lpb = (__half*)(Pexp + (size_t)APAD * V_);     // B*(U+1)*T fp16 log2
    __half* lpl = lpb + (size_t)B_ * (U_ + 1) * T_;        // B*U*T fp16 log2

    gemm1_kernel<<<dim3(V_/64, APAD/64), dim3(256), 0, stream>>>(
        enc, dec, W, bias, Pexp);

    gemm2_kernel<<<dim3(4, B_), dim3(256), 0, stream>>>(Pexp, targets, lpb, lpl);

    dp_kernel<<<dim3(B_), dim3(256), 0, stream>>>(lpb, lpl, tlen, ulen, out);
}

// Round 5
// 58.579 us; speedup vs baseline: 3.2435x; 1.0759x over previous
//
#include <hip/hip_runtime.h>
#include <hip/hip_fp16.h>
#include <math.h>

#define B_ 4
#define T_ 256
#define U_ 48
#define H_ 512
#define V_ 1024
#define BLANK_ (V_-1)

#define GM 1220        // B*T + B*(U+1)
#define GM_ENC 1024    // B*T
#define APAD 1280

#define NEGINF (-__builtin_inff())
#define INVLN2 1.4426950408889634f
#define LN2F   0.6931471805599453f

typedef __attribute__((ext_vector_type(8))) short short8;
typedef __attribute__((ext_vector_type(4))) float f32x4;

__device__ __forceinline__ unsigned short f2bf(float x) {
    union { float f; unsigned int u; } c; c.f = x;
    unsigned int r = c.u + 0x7FFF + ((c.u >> 16) & 1);   // RNE
    return (unsigned short)(r >> 16);
}
__device__ __forceinline__ float bf2f(unsigned short u) {
    union { unsigned int i; float f; } c; c.i = ((unsigned int)u) << 16; return c.f;
}
__device__ __forceinline__ unsigned int cvt_pk_bf16(float lo, float hi) {
    unsigned int r;
    asm("v_cvt_pk_bf16_f32 %0, %1, %2" : "=v"(r) : "v"(lo), "v"(hi));
    return r;
}
// wave-wide shift-right-by-1 via DPP (pure VALU: keeps lgkmcnt clean for payload prefetch)
__device__ __forceinline__ float wave_shr1(float x, float fill) {
    int r = __builtin_amdgcn_update_dpp(__builtin_bit_cast(int, fill),
                                        __builtin_bit_cast(int, x),
                                        0x138 /*wave_shr:1*/, 0xf, 0xf, false);
    return __builtin_bit_cast(float, r);
}

// ---------------- K1: Pexp = exp2(([enc;dec]@W^T + bias)·log2e) in bf16
// reg-prefetch pipeline: global loads for k+1 stay in flight across raw s_barriers.
__global__ __launch_bounds__(256) void gemm1_kernel(
    const float* __restrict__ enc, const float* __restrict__ dec,
    const float* __restrict__ W, const float* __restrict__ bias,
    unsigned short* __restrict__ Pexp)
{
    __shared__ __attribute__((aligned(16))) unsigned short As[64 * 64];
    __shared__ __attribute__((aligned(16))) unsigned short Bs[64 * 64];
    const int tid  = threadIdx.x;
    const int lane = tid & 63, wave = tid >> 6;
    const int wm = wave >> 1, wn = wave & 1;
    const int row0 = blockIdx.y * 64, col0 = blockIdx.x * 64;

    const int srow = tid >> 2;          // staging row 0..63
    const int scg  = (tid & 3) * 16;    // col group (fp32 elements)

    f32x4 acc[2][2];
    #pragma unroll
    for (int mi = 0; mi < 2; ++mi)
        #pragma unroll
        for (int ni = 0; ni < 2; ++ni)
            acc[mi][ni] = (f32x4){0.f, 0.f, 0.f, 0.f};

    float4 ra[4], rb[4];
    auto loadAB = [&](int k0) {
        float4 z = make_float4(0.f, 0.f, 0.f, 0.f);
        ra[0] = ra[1] = ra[2] = ra[3] = z;
        int gr = row0 + srow;
        if (gr < GM) {
            const float* s = (gr < GM_ENC)
                ? enc + (size_t)gr * H_ + k0 + scg
                : dec + (size_t)(gr - GM_ENC) * H_ + k0 + scg;
            ra[0] = *(const float4*)s;       ra[1] = *(const float4*)(s + 4);
            ra[2] = *(const float4*)(s + 8); ra[3] = *(const float4*)(s + 12);
        }
        const float* s = W + (size_t)(col0 + srow) * H_ + k0 + scg;
        rb[0] = *(const float4*)s;       rb[1] = *(const float4*)(s + 4);
        rb[2] = *(const float4*)(s + 8); rb[3] = *(const float4*)(s + 12);
    };
    auto stage = [&]() {
        uint4 w0 = { cvt_pk_bf16(ra[0].x, ra[0].y), cvt_pk_bf16(ra[0].z, ra[0].w),
                     cvt_pk_bf16(ra[1].x, ra[1].y), cvt_pk_bf16(ra[1].z, ra[1].w) };
        uint4 w1 = { cvt_pk_bf16(ra[2].x, ra[2].y), cvt_pk_bf16(ra[2].z, ra[2].w),
                     cvt_pk_bf16(ra[3].x, ra[3].y), cvt_pk_bf16(ra[3].z, ra[3].w) };
        uint4 v0 = { cvt_pk_bf16(rb[0].x, rb[0].y), cvt_pk_bf16(rb[0].z, rb[0].w),
                     cvt_pk_bf16(rb[1].x, rb[1].y), cvt_pk_bf16(rb[1].z, rb[1].w) };
        uint4 v1 = { cvt_pk_bf16(rb[2].x, rb[2].y), cvt_pk_bf16(rb[2].z, rb[2].w),
                     cvt_pk_bf16(rb[3].x, rb[3].y), cvt_pk_bf16(rb[3].z, rb[3].w) };
        int colb = scg * 2;
        int sw0 = (colb)      ^ ((srow & 7) << 4);
        int sw1 = (colb + 16) ^ ((srow & 7) << 4);
        *(uint4*)((char*)As + srow * 128 + sw0) = w0;
        *(uint4*)((char*)As + srow * 128 + sw1) = w1;
        *(uint4*)((char*)Bs + srow * 128 + sw0) = v0;
        *(uint4*)((char*)Bs + srow * 128 + sw1) = v1;
    };
    auto compute = [&]() {
        #pragma unroll
        for (int kk = 0; kk < 2; ++kk) {
            short8 a[2], b[2];
            const int cb = kk * 64 + (lane >> 4) * 16;
            #pragma unroll
            for (int mi = 0; mi < 2; ++mi) {
                int r = wm * 32 + mi * 16 + (lane & 15);
                a[mi] = *(const short8*)((const char*)As + r * 128 + (cb ^ ((r & 7) << 4)));
            }
            #pragma unroll
            for (int ni = 0; ni < 2; ++ni) {
                int r = wn * 32 + ni * 16 + (lane & 15);
                b[ni] = *(const short8*)((const char*)Bs + r * 128 + (cb ^ ((r & 7) << 4)));
            }
            #pragma unroll
            for (int mi = 0; mi < 2; ++mi)
                #pragma unroll
                for (int ni = 0; ni < 2; ++ni)
                    asm("v_mfma_f32_16x16x32_bf16 %0, %1, %2, %0"
                        : "+v"(acc[mi][ni]) : "v"(a[mi]), "v"(b[ni]));
        }
    };

    loadAB(0);
    #pragma unroll
    for (int k0 = 0; k0 < H_; k0 += 64) {
        stage();                                          // vmcnt wait inserted here
        asm volatile("s_waitcnt lgkmcnt(0)" ::: "memory"); // ds_writes visible
        __builtin_amdgcn_s_barrier();                      // raw: vmcnt NOT drained
        if (k0 + 64 < H_) loadAB(k0 + 64);                 // prefetch under compute
        compute();                                         // lgkm drained by MFMA waits
        __builtin_amdgcn_s_barrier();
    }

    // epilogue: C/D layout col=lane&15, row=(lane>>4)*4+j
    #pragma unroll
    for (int ni = 0; ni < 2; ++ni) {
        int col = col0 + wn * 32 + ni * 16 + (lane & 15);
        float bb = bias[col];
        #pragma unroll
        for (int mi = 0; mi < 2; ++mi) {
            #pragma unroll
            for (int j = 0; j < 4; ++j) {
                int gr = row0 + wm * 32 + mi * 16 + (lane >> 4) * 4 + j;
                if (gr >= GM) continue;
                float v = acc[mi][ni][j] + (gr < GM_ENC ? bb : 0.f);
                float p = __builtin_amdgcn_exp2f(v * INVLN2);
                Pexp[(size_t)gr * V_ + col] = f2bf(p);
            }
        }
    }
}

// ---------------- K2: denom[bt,u] = <Pexp_enc[bt,:], Pexp_dec[bu,:]> via MFMA,
// epilogue writes lpb/lpl (log2-domain fp16, transposed [b][u][t]).
__global__ __launch_bounds__(256) void gemm2_kernel(
    const unsigned short* __restrict__ Pexp, const int* __restrict__ targets,
    __half* __restrict__ lpb, __half* __restrict__ lpl)
{
    __shared__ __attribute__((aligned(16))) unsigned short As[64 * 64];
    __shared__ __attribute__((aligned(16))) unsigned short Bs[64 * 64];
    __shared__ float rowb2[64];
    __shared__ float colb2[64];
    __shared__ float pdt2[64];
    __shared__ int   tgtc[64];
    const int tid  = threadIdx.x;
    const int lane = tid & 63, wave = tid >> 6;
    const int wm = wave >> 1, wn = wave & 1;
    const int mt = blockIdx.x, b = blockIdx.y;

    if (tid < 64) {
        size_t grow = (size_t)(b * 256 + mt * 64 + tid);
        rowb2[tid] = __builtin_amdgcn_logf(bf2f(Pexp[grow * V_ + BLANK_]));
        if (tid <= U_) {
            size_t drow = (size_t)(GM_ENC + b * (U_ + 1) + tid);
            colb2[tid] = __builtin_amdgcn_logf(bf2f(Pexp[drow * V_ + BLANK_]));
            if (tid < U_) {
                int tg = targets[b * U_ + tid];
                tgtc[tid] = tg;
                pdt2[tid] = __builtin_amdgcn_logf(bf2f(Pexp[drow * V_ + tg]));
            }
        }
    }

    f32x4 acc[2][2];
    #pragma unroll
    for (int mi = 0; mi < 2; ++mi)
        #pragma unroll
        for (int ni = 0; ni < 2; ++ni)
            acc[mi][ni] = (f32x4){0.f, 0.f, 0.f, 0.f};

    short8 a2[2], b2[2];
    auto loadT = [&](int k0) {
        #pragma unroll
        for (int c = 0; c < 2; ++c) {
            int off = (tid + 256 * c) * 16;
            int row = off >> 7, colb = off & 127;
            size_t arow = (size_t)(b * 256 + mt * 64 + row);
            a2[c] = *(const short8*)((const char*)Pexp + arow * (V_*2) + k0*2 + colb);
            size_t brow = (size_t)(GM_ENC + b * (U_ + 1) + (row <= U_ ? row : U_));
            b2[c] = *(const short8*)((const char*)Pexp + brow * (V_*2) + k0*2 + colb);
        }
    };
    auto stageT = [&]() {
        #pragma unroll
        for (int c = 0; c < 2; ++c) {
            int off = (tid + 256 * c) * 16;
            int row = off >> 7, colb = off & 127;
            int sw = colb ^ ((row & 7) << 4);
            *(short8*)((char*)As + row * 128 + sw) = a2[c];
            *(short8*)((char*)Bs + row * 128 + sw) = b2[c];
        }
    };

    loadT(0);
    for (int k0 = 0; k0 < V_; k0 += 64) {
        stageT();
        asm volatile("s_waitcnt lgkmcnt(0)" ::: "memory");
        __builtin_amdgcn_s_barrier();
        if (k0 + 64 < V_) loadT(k0 + 64);
        #pragma unroll
        for (int kk = 0; kk < 2; ++kk) {
            short8 a[2], bfr[2];
            const int cb = kk * 64 + (lane >> 4) * 16;
            #pragma unroll
            for (int mi = 0; mi < 2; ++mi) {
                int r = wm * 32 + mi * 16 + (lane & 15);
                a[mi] = *(const short8*)((const char*)As + r * 128 + (cb ^ ((r & 7) << 4)));
            }
            #pragma unroll
            for (int ni = 0; ni < 2; ++ni) {
                int r = wn * 32 + ni * 16 + (lane & 15);
                bfr[ni] = *(const short8*)((const char*)Bs + r * 128 + (cb ^ ((r & 7) << 4)));
            }
            #pragma unroll
            for (int mi = 0; mi < 2; ++mi)
                #pragma unroll
                for (int ni = 0; ni < 2; ++ni)
                    asm("v_mfma_f32_16x16x32_bf16 %0, %1, %2, %0"
                        : "+v"(acc[mi][ni]) : "v"(a[mi]), "v"(bfr[ni]));
        }
        __builtin_amdgcn_s_barrier();
    }
    // epilogue
    #pragma unroll
    for (int ni = 0; ni < 2; ++ni) {
        int u = wn * 32 + ni * 16 + (lane & 15);
        if (u > U_) continue;
        #pragma unroll
        for (int mi = 0; mi < 2; ++mi) {
            #pragma unroll
            for (int j = 0; j < 4; ++j) {
                int r = wm * 32 + mi * 16 + (lane >> 4) * 4 + j;
                int t = mt * 64 + r;
                float lse2 = __builtin_amdgcn_logf(acc[mi][ni][j]);
                lpb[(b * (U_ + 1) + u) * T_ + t] =
                    __float2half(rowb2[r] + colb2[u] - lse2);
                if (u < U_) {
                    float pe = bf2f(Pexp[(size_t)(b * 256 + t) * V_ + tgtc[u]]);
                    lpl[(b * U_ + u) * T_ + t] =
                        __float2half(__builtin_amdgcn_logf(pe) + pdt2[u] - lse2);
                }
            }
        }
    }
}

// logaddexp in log2 domain
__device__ __forceinline__ float lad2(float x, float y) {
    float mx = fmaxf(x, y);
    float mn = fminf(x, y);
    return mx + __builtin_amdgcn_logf(1.0f + __builtin_amdgcn_exp2f(mn - mx));
}

// ---------------- K3: RNN-T alpha DP (t-block wavefront; DPP boundary pass)
__global__ __launch_bounds__(256) void dp_kernel(
    const __half* __restrict__ lpb, const __half* __restrict__ lpl,
    const int* __restrict__ tlen, const int* __restrict__ ulen,
    float* __restrict__ out)
{
    __shared__ __half slpb[(U_ + 1) * T_];
    __shared__ __half slpl[U_ * T_];
    const int b = blockIdx.x;
    const int tid = threadIdx.x;
    {
        const uint2* gb = (const uint2*)(lpb + (size_t)b * (U_ + 1) * T_);
        uint2* sb = (uint2*)slpb;
        for (int i = tid; i < (U_ + 1) * T_ / 4; i += 256) sb[i] = gb[i];
        const uint2* gl = (const uint2*)(lpl + (size_t)b * U_ * T_);
        uint2* sl = (uint2*)slpl;
        for (int i = tid; i < U_ * T_ / 4; i += 256) sl[i] = gl[i];
    }
    __syncthreads();
    if (tid >= 64) return;

    const int l = tid;
    const int t0 = 4 * l;
    const int TL = tlen[b], UL = ulen[b];
    const int lt = (TL - 1) >> 2;
    const int smax = lt + UL;

    float pu0 = NEGINF, pu1 = NEGINF, pu2 = NEGINF, pu3 = NEGINF;
    float a3 = NEGINF;
    float r0 = 0.f, r1 = 0.f, r2 = 0.f, r3 = 0.f;

    uint2 bq, lq; __half bx;
    auto issue = [&](int ss, uint2& obq, uint2& olq, __half& obx) {
        int uu = ss - l;
        int ub  = min(max(uu, 0), U_);
        int ul2 = min(max(uu - 1, 0), U_ - 1);
        obq = *(const uint2*)(slpb + ub * T_ + t0);
        olq = *(const uint2*)(slpl + ul2 * T_ + t0);
        obx = slpb[ub * T_ + (t0 > 0 ? t0 - 1 : 0)];
    };
    issue(0, bq, lq, bx);

    for (int s = 0; s <= smax; ++s) {
        // payload (ds_reads issued a full superstep ago) -> floats
        const __half2* bh = (const __half2*)&bq;
        float2 b01 = __half22float2(bh[0]);
        float2 b23 = __half22float2(bh[1]);
        const __half2* lh = (const __half2*)&lq;
        float2 l01 = __half22float2(lh[0]);
        float2 l23 = __half22float2(lh[1]);
        float B0 = __half2float(bx);
        float B1 = b01.x, B2 = b01.y, B3 = b23.x;
        float L0 = l01.x, L1 = l01.y, L2 = l23.x, L3 = l23.y;

        // neighbor boundary via DPP: pure VALU, no lgkm coupling with prefetch
        float bound = wave_shr1(a3, NEGINF);

        // prefetch next payload; completes during the lad2 chain
        uint2 nbq, nlq; __half nbx;
        issue(s + 1, nbq, nlq, nbx);

        int u = s - l;
        if (u >= 0 && u <= U_) {
            float y0 = pu0 + L0, y1 = pu1 + L1, y2 = pu2 + L2, y3 = pu3 + L3;
            float a0 = lad2(bound + B0, y0);
            if (l == 0 && u == 0) a0 = 0.f;
            float a1 = lad2(a0 + B1, y1);
            float a2 = lad2(a1 + B2, y2);
            float a3n = lad2(a2 + B3, y3);
            pu0 = a0; pu1 = a1; pu2 = a2; pu3 = a3n;
            a3 = a3n;
            if (u == UL && l == lt) { r0 = a0; r1 = a1; r2 = a2; r3 = a3n; }
        }
        bq = nbq; lq = nlq; bx = nbx;
    }

    if (l == lt) {
        int j = (TL - 1) & 3;
        float a = (j == 0) ? r0 : (j == 1) ? r1 : (j == 2) ? r2 : r3;
        float lb = __half2float(slpb[UL * T_ + (TL - 1)]);
        out[b] = -(a + lb) * LN2F;
    }
}

extern "C" void kernel_launch(void* const* d_in, const int* in_sizes, int n_in,
                              void* d_out, int out_size, void* d_ws, size_t ws_size,
                              hipStream_t stream) {
    const float* enc     = (const float*)d_in[0];
    const float* dec     = (const float*)d_in[1];
    const float* W       = (const float*)d_in[2];
    const float* bias    = (const float*)d_in[3];
    const int*   targets = (const int*)d_in[4];
    const int*   tlen    = (const int*)d_in[5];
    const int*   ulen    = (const int*)d_in[6];
    float* out = (float*)d_out;

    unsigned short* Pexp = (unsigned short*)d_ws;          // APAD x V bf16
    __half* lpb = (__half*)(Pexp + (size_t)APAD * V_);     // B*(U+1)*T fp16 log2
    __half* lpl = lpb + (size_t)B_ * (U_ + 1) * T_;        // B*U*T fp16 log2

    gemm1_kernel<<<dim3(V_/64, APAD/64), dim3(256), 0, stream>>>(
        enc, dec, W, bias, Pexp);

    gemm2_kernel<<<dim3(4, B_), dim3(256), 0, stream>>>(Pexp, targets, lpb, lpl);

    dp_kernel<<<dim3(B_), dim3(256), 0, stream>>>(lpb, lpl, tlen, ulen, out);
}